// Round 1
// baseline (417.485 us; speedup 1.0000x reference)
//
#include <hip/hip_runtime.h>

#define N_TOK 8192
#define D_IN 384
#define D_H 64
#define NHEADS 4
#define NSPLIT 4
#define N_CLS 6
#define LN_EPS 1e-5f

typedef __attribute__((ext_vector_type(8))) short short8;
typedef __attribute__((ext_vector_type(4))) float f32x4;

#define L2E2 2.08136898100560774f   /* (log2 e)^2 */

__device__ __forceinline__ unsigned short f2bf(float f) {
    unsigned int u = __float_as_uint(f);
    u += 0x7FFFu + ((u >> 16) & 1u);          // RNE (finite values only here)
    return (unsigned short)(u >> 16);
}
__device__ __forceinline__ float bf2f(unsigned short s) {
    return __uint_as_float(((unsigned int)s) << 16);
}

// Permuted key position within a 64-key tile (pairs bf16 cols for packed LDS
// writes in flash). P-columns and V-rows share the bijection -> PV invariant.
__device__ __forceinline__ int kperm(int k) {
    return (k & 32) + 2 * (k & 15) + ((k >> 4) & 1);
}

// ---------------------------------------------------------------------------
// Fused stage 1 (r9's proven version). 256 blocks x 512 thr:
// phase 1: 8 waves x 4 rows each -> h in LDS; phase 2: wave wv -> head wv>>1,
// half wv&1 (16 rows). Outputs: hp bf16 coalesced; Vf bf16 key-permuted
// coalesced b128; ssq2 = (sum hp^2)*(log2 e)^2.
// NO cooperative / fence / finisher variants: r10 (grid.sync) and r12
// (per-block threadfence) both flushed L2 device-wide and lost 2-3x.
// ---------------------------------------------------------------------------
__global__ __launch_bounds__(512) void stage1_kernel(
    const float* __restrict__ x, const float* __restrict__ proj_w,
    const float* __restrict__ proj_b, const float* __restrict__ head_w,
    const float* __restrict__ head_b,
    unsigned short* __restrict__ hp, unsigned short* __restrict__ Vf,
    float* __restrict__ ssq2)
{
    const int lane = threadIdx.x & 63;
    const int wv   = threadIdx.x >> 6;       // 0..7
    const int rb0  = blockIdx.x * 32;

    __shared__ float h_sh[32][68];                          // [row][feat]
    __shared__ __align__(16) unsigned short vt[NHEADS][4][64][8];

    // ---- phase 1: h = relu(x @ proj_w + b), 4 rows per wave ----
    {
        float acc[4];
        float b = proj_b[lane];
        #pragma unroll
        for (int r = 0; r < 4; ++r) acc[r] = b;
        const float* x0 = x + (size_t)(rb0 + wv * 4) * D_IN;
        #pragma unroll 2
        for (int k4 = 0; k4 < D_IN / 4; ++k4) {
            float w0 = proj_w[(k4 * 4 + 0) * 64 + lane];
            float w1 = proj_w[(k4 * 4 + 1) * 64 + lane];
            float w2 = proj_w[(k4 * 4 + 2) * 64 + lane];
            float w3 = proj_w[(k4 * 4 + 3) * 64 + lane];
            #pragma unroll
            for (int r = 0; r < 4; ++r) {
                float4 xv = *(const float4*)(x0 + r * D_IN + k4 * 4); // wave-uniform
                acc[r] = fmaf(xv.x, w0, acc[r]);
                acc[r] = fmaf(xv.y, w1, acc[r]);
                acc[r] = fmaf(xv.z, w2, acc[r]);
                acc[r] = fmaf(xv.w, w3, acc[r]);
            }
        }
        #pragma unroll
        for (int r = 0; r < 4; ++r)
            h_sh[wv * 4 + r][lane] = fmaxf(acc[r], 0.f);
    }
    __syncthreads();

    // ---- phase 2: hp = h @ head_w[head] + head_b[head]; 16 rows per wave ----
    const int head = wv >> 1;
    const int half = wv & 1;
    float a[16];
    {
        float b = head_b[head * 64 + lane];
        #pragma unroll
        for (int r = 0; r < 16; ++r) a[r] = b;
    }
    const float* wb = head_w + head * 64 * 64;
    #pragma unroll 2
    for (int e4 = 0; e4 < 16; ++e4) {
        float w0 = wb[(e4 * 4 + 0) * 64 + lane];
        float w1 = wb[(e4 * 4 + 1) * 64 + lane];
        float w2 = wb[(e4 * 4 + 2) * 64 + lane];
        float w3 = wb[(e4 * 4 + 3) * 64 + lane];
        #pragma unroll
        for (int r = 0; r < 16; ++r) {
            float4 hv = *(const float4*)&h_sh[half * 16 + r][e4 * 4]; // uniform b128
            a[r] = fmaf(hv.x, w0, a[r]);
            a[r] = fmaf(hv.y, w1, a[r]);
            a[r] = fmaf(hv.z, w2, a[r]);
            a[r] = fmaf(hv.w, w3, a[r]);
        }
    }

    #pragma unroll
    for (int r = 0; r < 16; ++r) {
        int kl  = half * 16 + r;
        int row = rb0 + kl;
        unsigned short hb = f2bf(a[r]);
        float hf = bf2f(hb);
        hp[((size_t)head * N_TOK + row) * 64 + lane] = hb;
        int p = kperm(row & 63);              // halves write disjoint even/odd
        vt[head][(p >> 3) & 3][lane][p & 7] = hb;
        float s = hf * hf;
        #pragma unroll
        for (int off = 32; off > 0; off >>= 1) s += __shfl_xor(s, off);
        if (lane == 0) ssq2[head * N_TOK + row] = s * L2E2;
    }
    __syncthreads();

    // ---- write Vf coalesced: 1024 chunks of 16B, 2 per thread ----
    const int kgbase = (rb0 & 32) ? 4 : 0;
    #pragma unroll
    for (int i = 0; i < 2; ++i) {
        int c  = threadIdx.x + 512 * i;
        int hc = c >> 8, rem = c & 255;
        int kg = rem >> 6, d = rem & 63;
        short8 v = *(const short8*)&vt[hc][kg][d][0];
        *(short8*)&Vf[(((size_t)hc * (N_TOK / 8) + (rb0 >> 6) * 8 + kgbase + kg) * 64
                       + d) * 8] = v;
    }
}

// ---------------------------------------------------------------------------
// Flash distance-attention, OCCUPANCY build (this round's change).
// Counter model (r13 profile): MfmaUtil 19 + VALUBusy 39 -> 42% un-issued;
// per-wave VALU demand model matches VALUBusy exactly, so the gap is stalls
// 4 waves/SIMD can't cover. Occupancy was double-capped: grid 1024 blocks =
// 4 blocks/CU AND ~124 regs -> 128-granule -> 4 waves/SIMD.
// Fix: 16 q-rows/wave (was 32), grid.y 64->128 (2048 blocks = 8 blocks/CU),
// __launch_bounds__(256,8) to pin the 64-VGPR allocation step. The explicit
// next-tile kA/bV1 prefetch is DROPPED: it existed for ILP at 4 waves and
// cost 16 regs; at 8 waves TLP hides the L2 latency. Total per-SIMD work is
// unchanged (same trans/VALU/MFMA per q-row; K/V re-reads stay L2-resident).
// Go/no-go: VGPR_Count must report <=64; if 65+, allocator spills -> revert.
// Max logit 0 (diagonal) -> no online rescaling. p = exp2(-sqrt(sq'));
// P packed bf16 pairs (kperm); O bf16. Grid (16 combos, 128 q-blocks);
// combo%8 -> one head per XCD (id = combo + 16*y keeps that property).
// ---------------------------------------------------------------------------
__global__ __launch_bounds__(256, 8) void flash_kernel(
    const unsigned short* __restrict__ hp, const unsigned short* __restrict__ Vf,
    const float* __restrict__ ssq2, unsigned short* __restrict__ Og,
    float* __restrict__ Lg)
{
    const int head  = blockIdx.x & 3;        // combo = split*NHEADS+head
    const int split = blockIdx.x >> 2;
    const int q0    = blockIdx.y * 64;
    const int w     = threadIdx.x >> 6;
    const int lane  = threadIdx.x & 63;
    const int col   = lane & 15;
    const int quad  = lane >> 4;

    __shared__ __align__(16) unsigned short Psh[4][16][72];

    const unsigned short* hpH = hp + head * (N_TOK * 64);
    const unsigned short* VfH = Vf + head * (N_TOK * 64);
    const float* ssqH = ssq2 + head * N_TOK;

    const int rb = q0 + w * 16;              // this wave's 16 q-rows

    short8 aQ0, aQ1;
    float ssqn2[4];
    {
        const unsigned short* qrow = hpH + (rb + col) * 64;
        aQ0 = *(const short8*)(qrow + quad * 8);
        aQ1 = *(const short8*)(qrow + 32 + quad * 8);
        #pragma unroll
        for (int r = 0; r < 4; ++r)
            ssqn2[r] = ssqH[rb + quad * 4 + r];
    }

    const f32x4 zero4 = {0.f, 0.f, 0.f, 0.f};
    f32x4 accO[4] = {zero4, zero4, zero4, zero4};
    f32x4 accL = zero4;
    const short8 ones = {16256,16256,16256,16256,16256,16256,16256,16256}; // bf16 1.0
    const float NEG2L2 = -2.0f * L2E2;

    const int ktps = N_TOK / 64 / NSPLIT;    // 32
    const int kt0  = split * ktps;
    const int ktend = kt0 + ktps;

    #pragma unroll 1
    for (int kt = kt0; kt < ktend; ++kt) {
        const unsigned short* kb = hpH + kt * 4096;
        const unsigned short* vb = VfH + kt * 4096;

        // ---- half A: S for keys 0..31 (K frags loaded per-nt: 8 regs live) --
        f32x4 aSA0 = zero4, aSA1 = zero4;
        {
            const unsigned short* kr = kb + col * 64 + quad * 8;
            short8 k0 = *(const short8*)kr;
            short8 k1 = *(const short8*)(kr + 32);
            aSA0 = __builtin_amdgcn_mfma_f32_16x16x32_bf16(aQ0, k0, aSA0, 0, 0, 0);
            aSA0 = __builtin_amdgcn_mfma_f32_16x16x32_bf16(aQ1, k1, aSA0, 0, 0, 0);
            k0 = *(const short8*)(kr + 16 * 64);
            k1 = *(const short8*)(kr + 16 * 64 + 32);
            aSA1 = __builtin_amdgcn_mfma_f32_16x16x32_bf16(aQ0, k0, aSA1, 0, 0, 0);
            aSA1 = __builtin_amdgcn_mfma_f32_16x16x32_bf16(aQ1, k1, aSA1, 0, 0, 0);
        }

        // softmax A -> write d0 (cols 0..31); aSA dies here
        {
            float sm0 = ssqH[kt * 64 + col];
            float sm1 = ssqH[kt * 64 + 16 + col];
            #pragma unroll
            for (int r = 0; r < 4; ++r) {
                float sq0 = fmaf(aSA0[r], NEG2L2, ssqn2[r] + sm0);
                float pf0 = __builtin_amdgcn_exp2f(-__builtin_amdgcn_sqrtf(fmaxf(sq0, 0.f)));
                float sq1 = fmaf(aSA1[r], NEG2L2, ssqn2[r] + sm1);
                float pf1 = __builtin_amdgcn_exp2f(-__builtin_amdgcn_sqrtf(fmaxf(sq1, 0.f)));
                unsigned int d0 = __builtin_amdgcn_perm(__float_as_uint(pf1),
                                                        __float_as_uint(pf0), 0x07060302u);
                *(unsigned int*)&Psh[w][quad * 4 + r][2 * col] = d0;
            }
        }

        // ---- half B: S for keys 32..63 ----
        f32x4 aSB0 = zero4, aSB1 = zero4;
        {
            const unsigned short* kr = kb + (32 + col) * 64 + quad * 8;
            short8 k0 = *(const short8*)kr;
            short8 k1 = *(const short8*)(kr + 32);
            aSB0 = __builtin_amdgcn_mfma_f32_16x16x32_bf16(aQ0, k0, aSB0, 0, 0, 0);
            aSB0 = __builtin_amdgcn_mfma_f32_16x16x32_bf16(aQ1, k1, aSB0, 0, 0, 0);
            k0 = *(const short8*)(kr + 16 * 64);
            k1 = *(const short8*)(kr + 16 * 64 + 32);
            aSB1 = __builtin_amdgcn_mfma_f32_16x16x32_bf16(aQ0, k0, aSB1, 0, 0, 0);
            aSB1 = __builtin_amdgcn_mfma_f32_16x16x32_bf16(aQ1, k1, aSB1, 0, 0, 0);
        }

        // softmax B -> write d1 (cols 32..63)
        {
            float sm2v = ssqH[kt * 64 + 32 + col];
            float sm3v = ssqH[kt * 64 + 48 + col];
            #pragma unroll
            for (int r = 0; r < 4; ++r) {
                float sq2 = fmaf(aSB0[r], NEG2L2, ssqn2[r] + sm2v);
                float pf2 = __builtin_amdgcn_exp2f(-__builtin_amdgcn_sqrtf(fmaxf(sq2, 0.f)));
                float sq3 = fmaf(aSB1[r], NEG2L2, ssqn2[r] + sm3v);
                float pf3 = __builtin_amdgcn_exp2f(-__builtin_amdgcn_sqrtf(fmaxf(sq3, 0.f)));
                unsigned int d1 = __builtin_amdgcn_perm(__float_as_uint(pf3),
                                                        __float_as_uint(pf2), 0x07060302u);
                *(unsigned int*)&Psh[w][quad * 4 + r][32 + 2 * col] = d1;
            }
        }

        // diag tile: force p=1.0 exactly (same-wave LDS ops are in order)
        if (kt == (rb >> 6) && lane < 16) {
            int t = (rb >> 4) & 3;
            Psh[w][lane][((t & 2) << 4) + 2 * lane + (t & 1)] = 0x3F80;
        }

        // ---- PV: c=0 then c=1; bV reloaded per half (16 regs live) ----
        {
            short8 aP0 = *(const short8*)&Psh[w][col][quad * 8];
            short8 bV[4];
            #pragma unroll
            for (int dt = 0; dt < 4; ++dt)
                bV[dt] = *(const short8*)(vb + (quad * 64 + dt * 16 + col) * 8);
            accL = __builtin_amdgcn_mfma_f32_16x16x32_bf16(aP0, ones, accL, 0, 0, 0);
            #pragma unroll
            for (int dt = 0; dt < 4; ++dt)
                accO[dt] = __builtin_amdgcn_mfma_f32_16x16x32_bf16(aP0, bV[dt], accO[dt], 0, 0, 0);

            short8 aP1 = *(const short8*)&Psh[w][col][32 + quad * 8];
            #pragma unroll
            for (int dt = 0; dt < 4; ++dt)
                bV[dt] = *(const short8*)(vb + ((4 + quad) * 64 + dt * 16 + col) * 8);
            accL = __builtin_amdgcn_mfma_f32_16x16x32_bf16(aP1, ones, accL, 0, 0, 0);
            #pragma unroll
            for (int dt = 0; dt < 4; ++dt)
                accO[dt] = __builtin_amdgcn_mfma_f32_16x16x32_bf16(aP1, bV[dt], accO[dt], 0, 0, 0);
        }
    }

    // ---- epilogue: unnormalized O (bf16) and l (f32) for this split ----
    unsigned short* og = Og + (size_t)(split * NHEADS + head) * N_TOK * 64;
    float* lg = Lg + (size_t)(split * NHEADS + head) * N_TOK;
    #pragma unroll
    for (int r = 0; r < 4; ++r) {
        int row = rb + quad * 4 + r;
        #pragma unroll
        for (int dt = 0; dt < 4; ++dt)
            og[row * 64 + dt * 16 + col] = f2bf(accO[dt][r]);
        if (col == 0) lg[row] = accL[r];
    }
}

// ---------------------------------------------------------------------------
// Combine: merge NSPLIT splits, head-softmax mix, layernorm, FC. Wave per row.
// ---------------------------------------------------------------------------
__global__ __launch_bounds__(256) void combine_kernel(
    const unsigned short* __restrict__ Og, const float* __restrict__ Lg,
    const float* __restrict__ attn_w, const float* __restrict__ gamma,
    const float* __restrict__ beta, const float* __restrict__ fc_w,
    const float* __restrict__ fc_b, float* __restrict__ out)
{
    const int lane = threadIdx.x & 63;
    const int ty   = threadIdx.x >> 6;
    const int row  = blockIdx.x * 4 + ty;

    float a0 = attn_w[0], a1 = attn_w[1], a2 = attn_w[2], a3 = attn_w[3];
    float m = fmaxf(fmaxf(a0, a1), fmaxf(a2, a3));
    float e0 = __expf(a0 - m), e1 = __expf(a1 - m), e2 = __expf(a2 - m), e3 = __expf(a3 - m);
    float inv = 1.f / (e0 + e1 + e2 + e3);
    float aw[4] = {e0 * inv, e1 * inv, e2 * inv, e3 * inv};

    float c = 0.f;
    #pragma unroll
    for (int hh = 0; hh < NHEADS; ++hh) {
        float l = 0.f, o = 0.f;
        #pragma unroll
        for (int s = 0; s < NSPLIT; ++s) {
            l += Lg[(s * NHEADS + hh) * N_TOK + row];
            o += bf2f(Og[(size_t)((s * NHEADS + hh) * N_TOK + row) * 64 + lane]);
        }
        c += aw[hh] * o * __builtin_amdgcn_rcpf(l);
    }

    float s = c;
    #pragma unroll
    for (int off = 32; off > 0; off >>= 1) s += __shfl_xor(s, off);
    float mu = s * (1.f / 64.f);
    float d = c - mu;
    float v = d * d;
    #pragma unroll
    for (int off = 32; off > 0; off >>= 1) v += __shfl_xor(v, off);
    float normed = d * rsqrtf(v * (1.f / 64.f) + LN_EPS) * gamma[lane] + beta[lane];

    float lg[N_CLS];
    #pragma unroll
    for (int cc = 0; cc < N_CLS; ++cc) {
        float p = normed * fc_w[lane * N_CLS + cc];
        #pragma unroll
        for (int off = 32; off > 0; off >>= 1) p += __shfl_xor(p, off);
        lg[cc] = p;
    }
    if (lane == 0) {
        #pragma unroll
        for (int cc = 0; cc < N_CLS; ++cc)
            out[row * N_CLS + cc] = lg[cc] + fc_b[cc];
    }
}

// ---------------------------------------------------------------------------
extern "C" void kernel_launch(void* const* d_in, const int* in_sizes, int n_in,
                              void* d_out, int out_size, void* d_ws, size_t ws_size,
                              hipStream_t stream)
{
    const float* x      = (const float*)d_in[0];
    const float* proj_w = (const float*)d_in[1];
    const float* proj_b = (const float*)d_in[2];
    const float* head_w = (const float*)d_in[3];
    const float* head_b = (const float*)d_in[4];
    const float* attn_w = (const float*)d_in[5];
    const float* gamma  = (const float*)d_in[6];
    const float* beta   = (const float*)d_in[7];
    const float* fc_w   = (const float*)d_in[8];
    const float* fc_b   = (const float*)d_in[9];
    float* out = (float*)d_out;

    char* ws = (char*)d_ws;
    // ws layout (bytes):
    //   hp   bf16 [4][8192][64]        @ 0          (4 MB)
    //   Vf   bf16 [4][1024][64][8]     @ 4 MB       (4 MB, key-permuted)
    //   ssq2 f32  [4][8192]            @ 8 MB       (128 KB)
    //   Og   bf16 [4][4][8192][64]     @ 8M+128K    (16 MB)
    //   Lg   f32  [4][4][8192]         @ 24M+128K   (512 KB)
    unsigned short* hp = (unsigned short*)(ws);
    unsigned short* Vf = (unsigned short*)(ws + (4u << 20));
    float* ssq2 = (float*)(ws + (8u << 20));
    unsigned short* Og = (unsigned short*)(ws + (8u << 20) + (128u << 10));
    float* Lg   = (float*)(ws + (24u << 20) + (128u << 10));

    stage1_kernel<<<N_TOK / 32, 512, 0, stream>>>(x, proj_w, proj_b, head_w, head_b,
                                                  hp, Vf, ssq2);
    dim3 g2(NHEADS * NSPLIT, N_TOK / 64);  // combo fastest -> one head per XCD
    flash_kernel<<<g2, 256, 0, stream>>>(hp, Vf, ssq2, Og, Lg);
    combine_kernel<<<N_TOK / 4, 256, 0, stream>>>(Og, Lg, attn_w, gamma, beta,
                                                  fc_w, fc_b, out);
}

// Round 2
// 277.281 us; speedup vs baseline: 1.5056x; 1.5056x over previous
//
#include <hip/hip_runtime.h>

#define N_TOK 8192
#define D_IN 384
#define D_H 64
#define NHEADS 4
#define NSPLIT 4
#define N_CLS 6
#define LN_EPS 1e-5f

typedef __attribute__((ext_vector_type(8))) short short8;
typedef __attribute__((ext_vector_type(4))) float f32x4;

#define L2E2 2.08136898100560774f   /* (log2 e)^2 */

__device__ __forceinline__ unsigned short f2bf(float f) {
    unsigned int u = __float_as_uint(f);
    u += 0x7FFFu + ((u >> 16) & 1u);          // RNE (finite values only here)
    return (unsigned short)(u >> 16);
}
__device__ __forceinline__ float bf2f(unsigned short s) {
    return __uint_as_float(((unsigned int)s) << 16);
}

// Permuted key position within a 64-key tile (pairs bf16 cols for packed LDS
// writes in flash). P-columns and V-rows share the bijection -> PV invariant.
__device__ __forceinline__ int kperm(int k) {
    return (k & 32) + 2 * (k & 15) + ((k >> 4) & 1);
}

// ---------------------------------------------------------------------------
// Fused stage 1 (r9's proven version). 256 blocks x 512 thr:
// phase 1: 8 waves x 4 rows each -> h in LDS; phase 2: wave wv -> head wv>>1,
// half wv&1 (16 rows). Outputs: hp bf16 coalesced; Vf bf16 key-permuted
// coalesced b128; ssq2 = (sum hp^2)*(log2 e)^2.
// NO cooperative / fence / finisher variants: r10 (grid.sync) and r12
// (per-block threadfence) both flushed L2 device-wide and lost 2-3x.
// ---------------------------------------------------------------------------
__global__ __launch_bounds__(512) void stage1_kernel(
    const float* __restrict__ x, const float* __restrict__ proj_w,
    const float* __restrict__ proj_b, const float* __restrict__ head_w,
    const float* __restrict__ head_b,
    unsigned short* __restrict__ hp, unsigned short* __restrict__ Vf,
    float* __restrict__ ssq2)
{
    const int lane = threadIdx.x & 63;
    const int wv   = threadIdx.x >> 6;       // 0..7
    const int rb0  = blockIdx.x * 32;

    __shared__ float h_sh[32][68];                          // [row][feat]
    __shared__ __align__(16) unsigned short vt[NHEADS][4][64][8];

    // ---- phase 1: h = relu(x @ proj_w + b), 4 rows per wave ----
    {
        float acc[4];
        float b = proj_b[lane];
        #pragma unroll
        for (int r = 0; r < 4; ++r) acc[r] = b;
        const float* x0 = x + (size_t)(rb0 + wv * 4) * D_IN;
        #pragma unroll 2
        for (int k4 = 0; k4 < D_IN / 4; ++k4) {
            float w0 = proj_w[(k4 * 4 + 0) * 64 + lane];
            float w1 = proj_w[(k4 * 4 + 1) * 64 + lane];
            float w2 = proj_w[(k4 * 4 + 2) * 64 + lane];
            float w3 = proj_w[(k4 * 4 + 3) * 64 + lane];
            #pragma unroll
            for (int r = 0; r < 4; ++r) {
                float4 xv = *(const float4*)(x0 + r * D_IN + k4 * 4); // wave-uniform
                acc[r] = fmaf(xv.x, w0, acc[r]);
                acc[r] = fmaf(xv.y, w1, acc[r]);
                acc[r] = fmaf(xv.z, w2, acc[r]);
                acc[r] = fmaf(xv.w, w3, acc[r]);
            }
        }
        #pragma unroll
        for (int r = 0; r < 4; ++r)
            h_sh[wv * 4 + r][lane] = fmaxf(acc[r], 0.f);
    }
    __syncthreads();

    // ---- phase 2: hp = h @ head_w[head] + head_b[head]; 16 rows per wave ----
    const int head = wv >> 1;
    const int half = wv & 1;
    float a[16];
    {
        float b = head_b[head * 64 + lane];
        #pragma unroll
        for (int r = 0; r < 16; ++r) a[r] = b;
    }
    const float* wb = head_w + head * 64 * 64;
    #pragma unroll 2
    for (int e4 = 0; e4 < 16; ++e4) {
        float w0 = wb[(e4 * 4 + 0) * 64 + lane];
        float w1 = wb[(e4 * 4 + 1) * 64 + lane];
        float w2 = wb[(e4 * 4 + 2) * 64 + lane];
        float w3 = wb[(e4 * 4 + 3) * 64 + lane];
        #pragma unroll
        for (int r = 0; r < 16; ++r) {
            float4 hv = *(const float4*)&h_sh[half * 16 + r][e4 * 4]; // uniform b128
            a[r] = fmaf(hv.x, w0, a[r]);
            a[r] = fmaf(hv.y, w1, a[r]);
            a[r] = fmaf(hv.z, w2, a[r]);
            a[r] = fmaf(hv.w, w3, a[r]);
        }
    }

    #pragma unroll
    for (int r = 0; r < 16; ++r) {
        int kl  = half * 16 + r;
        int row = rb0 + kl;
        unsigned short hb = f2bf(a[r]);
        float hf = bf2f(hb);
        hp[((size_t)head * N_TOK + row) * 64 + lane] = hb;
        int p = kperm(row & 63);              // halves write disjoint even/odd
        vt[head][(p >> 3) & 3][lane][p & 7] = hb;
        float s = hf * hf;
        #pragma unroll
        for (int off = 32; off > 0; off >>= 1) s += __shfl_xor(s, off);
        if (lane == 0) ssq2[head * N_TOK + row] = s * L2E2;
    }
    __syncthreads();

    // ---- write Vf coalesced: 1024 chunks of 16B, 2 per thread ----
    const int kgbase = (rb0 & 32) ? 4 : 0;
    #pragma unroll
    for (int i = 0; i < 2; ++i) {
        int c  = threadIdx.x + 512 * i;
        int hc = c >> 8, rem = c & 255;
        int kg = rem >> 6, d = rem & 63;
        short8 v = *(const short8*)&vt[hc][kg][d][0];
        *(short8*)&Vf[(((size_t)hc * (N_TOK / 8) + (rb0 >> 6) * 8 + kgbase + kg) * 64
                       + d) * 8] = v;
    }
}

// ---------------------------------------------------------------------------
// Flash distance-attention. Base = r13 structure (proven 170 µs, 32 q-rows/
// wave, 4 waves/SIMD). r14 occupancy experiment (16 rows, 8 waves/SIMD,
// 64-reg class) REGRESSED 1.84x: same absolute MFMA/VALU work, double the
// K/V load traffic, no prefetch, stalls grew. DO NOT retry occupancy.
// This round: two latency cuts inside the 128-reg class:
//  (1) sm (key ||k||^2) prefetched one ktile ahead (issued in PV shadow,
//      +4 VGPR) — kills the exposed top-of-loop L2 latency before softmaxA.
//  (2) PV c=0 hoisted between half-B MFMAs and softmaxB: aP0/aP1 only need
//      the d0 writes (complete under 8 half-B MFMAs), and softmaxB's VALU
//      then co-issues against PV-c0's 10 MFMAs. Diag fix split lo/hi: both
//      s-tiles of a wave land entirely in d0 or d1 ((rb>>5)&1 decides).
// Max logit 0 (diagonal) -> no online rescaling. p = exp2(-sqrt(sq'));
// P packed bf16 pairs (kperm); O bf16. Grid (16 combos, 64 q-blocks);
// combo%8 -> one head per XCD.
// Go/no-go: OccupancyPercent ~44. If ~22, reorder spilled past 128 -> revert.
// ---------------------------------------------------------------------------
__global__ __launch_bounds__(256, 4) void flash_kernel(
    const unsigned short* __restrict__ hp, const unsigned short* __restrict__ Vf,
    const float* __restrict__ ssq2, unsigned short* __restrict__ Og,
    float* __restrict__ Lg)
{
    const int head  = blockIdx.x & 3;        // combo = split*NHEADS+head
    const int split = blockIdx.x >> 2;
    const int q0    = blockIdx.y * 128;
    const int w     = threadIdx.x >> 6;
    const int lane  = threadIdx.x & 63;
    const int col   = lane & 15;
    const int quad  = lane >> 4;

    __shared__ __align__(16) unsigned short Psh[4][2][16][72];

    const unsigned short* hpH = hp + head * (N_TOK * 64);
    const unsigned short* VfH = Vf + head * (N_TOK * 64);
    const float* ssqH = ssq2 + head * N_TOK;

    const int rb = q0 + w * 32;              // this wave's 32 q-rows
    const bool diag_lo = ((rb >> 5) & 1) == 0;  // both s-tiles hit d0 (else d1)

    short8 aQ[2][2];
    float ssqn2[2][4];
    #pragma unroll
    for (int s = 0; s < 2; ++s) {
        const unsigned short* qrow = hpH + (rb + s * 16 + col) * 64;
        aQ[s][0] = *(const short8*)(qrow + quad * 8);
        aQ[s][1] = *(const short8*)(qrow + 32 + quad * 8);
        #pragma unroll
        for (int r = 0; r < 4; ++r)
            ssqn2[s][r] = ssqH[rb + s * 16 + quad * 4 + r];
    }

    const f32x4 zero4 = {0.f, 0.f, 0.f, 0.f};
    f32x4 accO[2][4] = {{zero4, zero4, zero4, zero4}, {zero4, zero4, zero4, zero4}};
    f32x4 accL[2] = {zero4, zero4};
    const short8 ones = {16256,16256,16256,16256,16256,16256,16256,16256}; // bf16 1.0
    const float NEG2L2 = -2.0f * L2E2;

    const int ktps = N_TOK / 64 / NSPLIT;    // 32
    const int kt0  = split * ktps;
    const int ktend = kt0 + ktps;

    // prime the software pipeline: half-A K frags + sm (key ssq) for tile kt0
    short8 kA[4];
    float smc[4];
    {
        const unsigned short* kb0 = hpH + kt0 * 4096;
        #pragma unroll
        for (int nt = 0; nt < 2; ++nt) {
            const unsigned short* kr = kb0 + (nt * 16 + col) * 64 + quad * 8;
            kA[nt * 2 + 0] = *(const short8*)kr;
            kA[nt * 2 + 1] = *(const short8*)(kr + 32);
        }
        #pragma unroll
        for (int nt = 0; nt < 4; ++nt) smc[nt] = ssqH[kt0 * 64 + nt * 16 + col];
    }

    #pragma unroll 1
    for (int kt = kt0; kt < ktend; ++kt) {
        const unsigned short* kb = hpH + kt * 4096;
        const unsigned short* vb = VfH + kt * 4096;

        // ---- half A: S for keys 0..31 — K frags + sm already in registers ----
        f32x4 aSA[2][2] = {{zero4, zero4}, {zero4, zero4}};
        #pragma unroll
        for (int nt = 0; nt < 2; ++nt) {
            aSA[0][nt] = __builtin_amdgcn_mfma_f32_16x16x32_bf16(aQ[0][0], kA[nt * 2 + 0], aSA[0][nt], 0, 0, 0);
            aSA[0][nt] = __builtin_amdgcn_mfma_f32_16x16x32_bf16(aQ[0][1], kA[nt * 2 + 1], aSA[0][nt], 0, 0, 0);
            aSA[1][nt] = __builtin_amdgcn_mfma_f32_16x16x32_bf16(aQ[1][0], kA[nt * 2 + 0], aSA[1][nt], 0, 0, 0);
            aSA[1][nt] = __builtin_amdgcn_mfma_f32_16x16x32_bf16(aQ[1][1], kA[nt * 2 + 1], aSA[1][nt], 0, 0, 0);
        }

        // half-B K loads issued here: covered by softmax-A below (kA regs
        // are dead after the MFMAs above — reuse window, no extra pressure)
        short8 kB[4];
        #pragma unroll
        for (int nt = 0; nt < 2; ++nt) {
            const unsigned short* kr = kb + ((nt + 2) * 16 + col) * 64 + quad * 8;
            kB[nt * 2 + 0] = *(const short8*)kr;
            kB[nt * 2 + 1] = *(const short8*)(kr + 32);
        }

        // softmax A -> write d0 (cols 0..31); aSA dies here
        #pragma unroll
        for (int s = 0; s < 2; ++s) {
            float pf0[4], pf1[4];
            #pragma unroll
            for (int r = 0; r < 4; ++r) {
                float sq0 = fmaf(aSA[s][0][r], NEG2L2, ssqn2[s][r] + smc[0]);
                pf0[r] = __builtin_amdgcn_exp2f(-__builtin_amdgcn_sqrtf(fmaxf(sq0, 0.f)));
                float sq1 = fmaf(aSA[s][1][r], NEG2L2, ssqn2[s][r] + smc[1]);
                pf1[r] = __builtin_amdgcn_exp2f(-__builtin_amdgcn_sqrtf(fmaxf(sq1, 0.f)));
            }
            #pragma unroll
            for (int r = 0; r < 4; ++r) {
                unsigned int d0 = __builtin_amdgcn_perm(__float_as_uint(pf1[r]),
                                                        __float_as_uint(pf0[r]), 0x07060302u);
                *(unsigned int*)&Psh[w][s][quad * 4 + r][2 * col] = d0;
            }
        }
        // diag tile, lo half: both s-tiles' fixes land in cols 0..31
        if (diag_lo && kt == (rb >> 6) && lane < 16) {
            #pragma unroll
            for (int s = 0; s < 2; ++s) {
                int t = ((rb + s * 16) >> 4) & 3;      // 0 or 1
                Psh[w][s][lane][2 * lane + (t & 1)] = 0x3F80;
            }
        }

        // ---- half B: S for keys 32..63 ----
        f32x4 aSB[2][2] = {{zero4, zero4}, {zero4, zero4}};
        #pragma unroll
        for (int nt = 0; nt < 2; ++nt) {
            aSB[0][nt] = __builtin_amdgcn_mfma_f32_16x16x32_bf16(aQ[0][0], kB[nt * 2 + 0], aSB[0][nt], 0, 0, 0);
            aSB[0][nt] = __builtin_amdgcn_mfma_f32_16x16x32_bf16(aQ[0][1], kB[nt * 2 + 1], aSB[0][nt], 0, 0, 0);
            aSB[1][nt] = __builtin_amdgcn_mfma_f32_16x16x32_bf16(aQ[1][0], kB[nt * 2 + 0], aSB[1][nt], 0, 0, 0);
            aSB[1][nt] = __builtin_amdgcn_mfma_f32_16x16x32_bf16(aQ[1][1], kB[nt * 2 + 1], aSB[1][nt], 0, 0, 0);
        }

        // bV for c=0 issued here: latency covered by aP reads + PV-c0 setup
        short8 bV0[4];
        #pragma unroll
        for (int dt = 0; dt < 4; ++dt)
            bV0[dt] = *(const short8*)(vb + (quad * 64 + dt * 16 + col) * 8);

        // ---- PV c=0 (hoisted before softmaxB): aP needs only d0 writes,
        //      which completed under the 8 half-B MFMAs above. softmaxB's
        //      VALU below co-issues against these 10 MFMAs. ----
        {
            short8 aP0 = *(const short8*)&Psh[w][0][col][quad * 8];
            short8 aP1 = *(const short8*)&Psh[w][1][col][quad * 8];
            accL[0] = __builtin_amdgcn_mfma_f32_16x16x32_bf16(aP0, ones, accL[0], 0, 0, 0);
            accL[1] = __builtin_amdgcn_mfma_f32_16x16x32_bf16(aP1, ones, accL[1], 0, 0, 0);
            #pragma unroll
            for (int dt = 0; dt < 4; ++dt) {
                accO[0][dt] = __builtin_amdgcn_mfma_f32_16x16x32_bf16(aP0, bV0[dt], accO[0][dt], 0, 0, 0);
                accO[1][dt] = __builtin_amdgcn_mfma_f32_16x16x32_bf16(aP1, bV0[dt], accO[1][dt], 0, 0, 0);
            }
        }

        // softmax B -> write d1 (cols 32..63); aSB dies here
        #pragma unroll
        for (int s = 0; s < 2; ++s) {
            float pf2[4], pf3[4];
            #pragma unroll
            for (int r = 0; r < 4; ++r) {
                float sq2 = fmaf(aSB[s][0][r], NEG2L2, ssqn2[s][r] + smc[2]);
                pf2[r] = __builtin_amdgcn_exp2f(-__builtin_amdgcn_sqrtf(fmaxf(sq2, 0.f)));
                float sq3 = fmaf(aSB[s][1][r], NEG2L2, ssqn2[s][r] + smc[3]);
                pf3[r] = __builtin_amdgcn_exp2f(-__builtin_amdgcn_sqrtf(fmaxf(sq3, 0.f)));
            }
            #pragma unroll
            for (int r = 0; r < 4; ++r) {
                unsigned int d1 = __builtin_amdgcn_perm(__float_as_uint(pf3[r]),
                                                        __float_as_uint(pf2[r]), 0x07060302u);
                *(unsigned int*)&Psh[w][s][quad * 4 + r][32 + 2 * col] = d1;
            }
        }
        // diag tile, hi half: both s-tiles' fixes land in cols 32..63
        if (!diag_lo && kt == (rb >> 6) && lane < 16) {
            #pragma unroll
            for (int s = 0; s < 2; ++s) {
                int t = ((rb + s * 16) >> 4) & 3;      // 2 or 3
                Psh[w][s][lane][32 + 2 * lane + (t & 1)] = 0x3F80;
            }
        }

        // ---- prefetch next tile's half-A K frags + sm; bV1 loads ----
        {
            const int ktn = (kt + 1 < ktend) ? kt + 1 : kt0;
            const unsigned short* kbn = hpH + ktn * 4096;
            #pragma unroll
            for (int nt = 0; nt < 2; ++nt) {
                const unsigned short* kr = kbn + (nt * 16 + col) * 64 + quad * 8;
                kA[nt * 2 + 0] = *(const short8*)kr;
                kA[nt * 2 + 1] = *(const short8*)(kr + 32);
            }
            #pragma unroll
            for (int nt = 0; nt < 4; ++nt) smc[nt] = ssqH[ktn * 64 + nt * 16 + col];
        }
        short8 bV1[4];
        #pragma unroll
        for (int dt = 0; dt < 4; ++dt)
            bV1[dt] = *(const short8*)(vb + ((4 + quad) * 64 + dt * 16 + col) * 8);

        // ---- PV c=1 ----
        {
            short8 aP0b = *(const short8*)&Psh[w][0][col][32 + quad * 8];
            short8 aP1b = *(const short8*)&Psh[w][1][col][32 + quad * 8];
            accL[0] = __builtin_amdgcn_mfma_f32_16x16x32_bf16(aP0b, ones, accL[0], 0, 0, 0);
            accL[1] = __builtin_amdgcn_mfma_f32_16x16x32_bf16(aP1b, ones, accL[1], 0, 0, 0);
            #pragma unroll
            for (int dt = 0; dt < 4; ++dt) {
                accO[0][dt] = __builtin_amdgcn_mfma_f32_16x16x32_bf16(aP0b, bV1[dt], accO[0][dt], 0, 0, 0);
                accO[1][dt] = __builtin_amdgcn_mfma_f32_16x16x32_bf16(aP1b, bV1[dt], accO[1][dt], 0, 0, 0);
            }
        }
    }

    // ---- epilogue: unnormalized O (bf16) and l (f32) for this split ----
    unsigned short* og = Og + (size_t)(split * NHEADS + head) * N_TOK * 64;
    float* lg = Lg + (size_t)(split * NHEADS + head) * N_TOK;
    #pragma unroll
    for (int s = 0; s < 2; ++s)
        #pragma unroll
        for (int r = 0; r < 4; ++r) {
            int row = rb + s * 16 + quad * 4 + r;
            #pragma unroll
            for (int dt = 0; dt < 4; ++dt)
                og[row * 64 + dt * 16 + col] = f2bf(accO[s][dt][r]);
            if (col == 0) lg[row] = accL[s][r];
        }
}

// ---------------------------------------------------------------------------
// Combine: merge NSPLIT splits, head-softmax mix, layernorm, FC. Wave per row.
// ---------------------------------------------------------------------------
__global__ __launch_bounds__(256) void combine_kernel(
    const unsigned short* __restrict__ Og, const float* __restrict__ Lg,
    const float* __restrict__ attn_w, const float* __restrict__ gamma,
    const float* __restrict__ beta, const float* __restrict__ fc_w,
    const float* __restrict__ fc_b, float* __restrict__ out)
{
    const int lane = threadIdx.x & 63;
    const int ty   = threadIdx.x >> 6;
    const int row  = blockIdx.x * 4 + ty;

    float a0 = attn_w[0], a1 = attn_w[1], a2 = attn_w[2], a3 = attn_w[3];
    float m = fmaxf(fmaxf(a0, a1), fmaxf(a2, a3));
    float e0 = __expf(a0 - m), e1 = __expf(a1 - m), e2 = __expf(a2 - m), e3 = __expf(a3 - m);
    float inv = 1.f / (e0 + e1 + e2 + e3);
    float aw[4] = {e0 * inv, e1 * inv, e2 * inv, e3 * inv};

    float c = 0.f;
    #pragma unroll
    for (int hh = 0; hh < NHEADS; ++hh) {
        float l = 0.f, o = 0.f;
        #pragma unroll
        for (int s = 0; s < NSPLIT; ++s) {
            l += Lg[(s * NHEADS + hh) * N_TOK + row];
            o += bf2f(Og[(size_t)((s * NHEADS + hh) * N_TOK + row) * 64 + lane]);
        }
        c += aw[hh] * o * __builtin_amdgcn_rcpf(l);
    }

    float s = c;
    #pragma unroll
    for (int off = 32; off > 0; off >>= 1) s += __shfl_xor(s, off);
    float mu = s * (1.f / 64.f);
    float d = c - mu;
    float v = d * d;
    #pragma unroll
    for (int off = 32; off > 0; off >>= 1) v += __shfl_xor(v, off);
    float normed = d * rsqrtf(v * (1.f / 64.f) + LN_EPS) * gamma[lane] + beta[lane];

    float lg[N_CLS];
    #pragma unroll
    for (int cc = 0; cc < N_CLS; ++cc) {
        float p = normed * fc_w[lane * N_CLS + cc];
        #pragma unroll
        for (int off = 32; off > 0; off >>= 1) p += __shfl_xor(p, off);
        lg[cc] = p;
    }
    if (lane == 0) {
        #pragma unroll
        for (int cc = 0; cc < N_CLS; ++cc)
            out[row * N_CLS + cc] = lg[cc] + fc_b[cc];
    }
}

// ---------------------------------------------------------------------------
extern "C" void kernel_launch(void* const* d_in, const int* in_sizes, int n_in,
                              void* d_out, int out_size, void* d_ws, size_t ws_size,
                              hipStream_t stream)
{
    const float* x      = (const float*)d_in[0];
    const float* proj_w = (const float*)d_in[1];
    const float* proj_b = (const float*)d_in[2];
    const float* head_w = (const float*)d_in[3];
    const float* head_b = (const float*)d_in[4];
    const float* attn_w = (const float*)d_in[5];
    const float* gamma  = (const float*)d_in[6];
    const float* beta   = (const float*)d_in[7];
    const float* fc_w   = (const float*)d_in[8];
    const float* fc_b   = (const float*)d_in[9];
    float* out = (float*)d_out;

    char* ws = (char*)d_ws;
    // ws layout (bytes):
    //   hp   bf16 [4][8192][64]        @ 0          (4 MB)
    //   Vf   bf16 [4][1024][64][8]     @ 4 MB       (4 MB, key-permuted)
    //   ssq2 f32  [4][8192]            @ 8 MB       (128 KB)
    //   Og   bf16 [4][4][8192][64]     @ 8M+128K    (16 MB)
    //   Lg   f32  [4][4][8192]         @ 24M+128K   (512 KB)
    unsigned short* hp = (unsigned short*)(ws);
    unsigned short* Vf = (unsigned short*)(ws + (4u << 20));
    float* ssq2 = (float*)(ws + (8u << 20));
    unsigned short* Og = (unsigned short*)(ws + (8u << 20) + (128u << 10));
    float* Lg   = (float*)(ws + (24u << 20) + (128u << 10));

    stage1_kernel<<<N_TOK / 32, 512, 0, stream>>>(x, proj_w, proj_b, head_w, head_b,
                                                  hp, Vf, ssq2);
    dim3 g2(NHEADS * NSPLIT, N_TOK / 128);  // combo fastest -> one head per XCD
    flash_kernel<<<g2, 256, 0, stream>>>(hp, Vf, ssq2, Og, Lg);
    combine_kernel<<<N_TOK / 4, 256, 0, stream>>>(Og, Lg, attn_w, gamma, beta,
                                                  fc_w, fc_b, out);
}